// Round 5
// baseline (201.778 us; speedup 1.0000x reference)
//
#include <hip/hip_runtime.h>
#include <math.h>

// BERT-CRF forward NLL on MI355X — register-only serial recursion.
// One item per 64-lane wave, p duplicated mod 32 across halves.
// Matvec via XOR shuffle tree (depth<=3) instead of serial rotations:
//   q[j] = sum_{r=0..31} p[j^r] * E[j^r][j]
// masks 1..15: pure in-row DPP (quad_perm / half_mirror / mirror + compose)
// masks 16..31: one ds_swizzle (xor16) issued at END of previous step, then
//               the same DPP tree on it — DS latency overlapped.
// Gold score computed as a parallel gather tail after the recursion.

constexpr int NTAG = 32;
constexpr int TSTART = 30;
constexpr int TSTOP = 31;
constexpr int NB = 1024;
constexpr int NS = 512;

constexpr float LOG2E = 1.44269504088896340736f;
constexpr float LN2   = 0.69314718055994530942f;

// DPP ctrl codes
constexpr int DPP_X1 = 0xB1;   // quad_perm [1,0,3,2]  (lane ^ 1)
constexpr int DPP_X2 = 0x4E;   // quad_perm [2,3,0,1]  (lane ^ 2)
constexpr int DPP_X3 = 0x1B;   // quad_perm [3,2,1,0]  (lane ^ 3)
constexpr int DPP_X7 = 0x141;  // row_half_mirror      (lane ^ 7)
constexpr int DPP_XF = 0x140;  // row_mirror           (lane ^ 15)

template <int CTRL>
__device__ __forceinline__ float dppf(float x) {
    return __int_as_float(__builtin_amdgcn_update_dpp(
        0, __float_as_int(x), CTRL, 0xF, 0xF, false));
}
__device__ __forceinline__ float swz16(float x) {  // lane ^ 16 within 32-groups
    return __int_as_float(__builtin_amdgcn_ds_swizzle(__float_as_int(x), 0x401F));
}
__device__ __forceinline__ float fexp2(float x) {
#if __has_builtin(__builtin_amdgcn_exp2f)
    return __builtin_amdgcn_exp2f(x);
#else
    return exp2f(x);
#endif
}

__global__ __launch_bounds__(64)
void crf_fwd(const float* __restrict__ feats,
             const int*   __restrict__ labels,
             const int*   __restrict__ lengths,
             const float* __restrict__ trans,
             float*       __restrict__ out)
{
    const int j   = threadIdx.x;   // 0..63
    const int j32 = j & 31;
    const int b   = blockIdx.x;

    // Per-lane coefficients: EC[r] = exp(trans[(j32^r)][j32]), r = 0..31
    float EC[32];
    #pragma unroll
    for (int r = 0; r < 32; ++r)
        EC[r] = fexp2(trans[((j32 ^ r) << 5) + j32] * LOG2E);

    const int len = lengths[b];
    const float* fb = feats  + (size_t)b * NS * NTAG;
    const int*   lb = labels + (size_t)b * NS;

    // t = 0
    float feat0 = fb[j32];
    float p  = fexp2((feat0 + trans[(TSTART << 5) + j32]) * LOG2E);
    float pX = swz16(p);   // p[j^16], for masks 16..31 of the first step

    int bits0 = __builtin_amdgcn_readfirstlane(__float_as_int(p));
    int e0    = min(max((bits0 >> 23) & 0xFF, 1), 254);
    int kreg  = e0 - 127;
    int creg  = 0;

    // feats prefetch pipeline (8 deep)
    float pf[8];
    #pragma unroll
    for (int u = 0; u < 8; ++u) {
        int tt = min(1 + u, NS - 1);
        pf[u] = fb[(size_t)tt * NTAG + j32];
    }

    const int nsteps = len - 1;        // recursion steps t = 1..len-1
    const int nchunk = nsteps >> 3;
    const int rem    = nsteps & 7;
    int t = 1;

    #define CRF_STEP(FEAT)                                                   \
    {                                                                        \
        float feat_ = (FEAT);                                                \
        /* off-chain: emission factor with folded 2^-k */                    \
        creg += kreg;                                                        \
        float F = fexp2(fmaf(feat_, LOG2E, -(float)kreg));                   \
        /* lower xor tree from p (masks 1..15), depth <= 3, all in-row */    \
        float v1  = dppf<DPP_X1>(p);                                         \
        float v2  = dppf<DPP_X2>(p);                                         \
        float v3  = dppf<DPP_X3>(p);                                         \
        float v7  = dppf<DPP_X7>(p);                                         \
        float v15 = dppf<DPP_XF>(p);                                         \
        float v4  = dppf<DPP_X3>(v7);                                        \
        float v5  = dppf<DPP_X2>(v7);                                        \
        float v6  = dppf<DPP_X1>(v7);                                        \
        float v8  = dppf<DPP_X7>(v15);                                       \
        float v12 = dppf<DPP_X3>(v15);                                       \
        float v13 = dppf<DPP_X2>(v15);                                       \
        float v14 = dppf<DPP_X1>(v15);                                       \
        float v9  = dppf<DPP_X1>(v8);                                        \
        float v10 = dppf<DPP_X2>(v8);                                        \
        float v11 = dppf<DPP_X3>(v8);                                        \
        float aA = p * EC[0];                                                \
        aA = fmaf(v1,  EC[1],  aA);                                          \
        float aB = v2 * EC[2];                                               \
        aB = fmaf(v3,  EC[3],  aB);                                          \
        float aC = v7 * EC[7];                                               \
        aC = fmaf(v15, EC[15], aC);                                          \
        float aD = v4 * EC[4];                                               \
        aD = fmaf(v5,  EC[5],  aD);                                          \
        aA = fmaf(v6,  EC[6],  aA);                                          \
        aB = fmaf(v8,  EC[8],  aB);                                          \
        aC = fmaf(v12, EC[12], aC);                                          \
        aD = fmaf(v13, EC[13], aD);                                          \
        aA = fmaf(v14, EC[14], aA);                                          \
        aB = fmaf(v9,  EC[9],  aB);                                          \
        aC = fmaf(v10, EC[10], aC);                                          \
        aD = fmaf(v11, EC[11], aD);                                          \
        /* upper xor tree from pX = p[j^16] (masks 16..31) */                \
        float w1  = dppf<DPP_X1>(pX);                                        \
        float w2  = dppf<DPP_X2>(pX);                                        \
        float w3  = dppf<DPP_X3>(pX);                                        \
        float w7  = dppf<DPP_X7>(pX);                                        \
        float w15 = dppf<DPP_XF>(pX);                                        \
        float w4  = dppf<DPP_X3>(w7);                                        \
        float w5  = dppf<DPP_X2>(w7);                                        \
        float w6  = dppf<DPP_X1>(w7);                                        \
        float w8  = dppf<DPP_X7>(w15);                                       \
        float w12 = dppf<DPP_X3>(w15);                                       \
        float w13 = dppf<DPP_X2>(w15);                                       \
        float w14 = dppf<DPP_X1>(w15);                                       \
        float w9  = dppf<DPP_X1>(w8);                                        \
        float w10 = dppf<DPP_X2>(w8);                                        \
        float w11 = dppf<DPP_X3>(w8);                                        \
        float aE = pX * EC[16];                                              \
        aE = fmaf(w1,  EC[17], aE);                                          \
        float aF_ = w2 * EC[18];                                             \
        aF_ = fmaf(w3,  EC[19], aF_);                                        \
        float aG = w7 * EC[23];                                              \
        aG = fmaf(w15, EC[31], aG);                                          \
        float aH = w4 * EC[20];                                              \
        aH = fmaf(w5,  EC[21], aH);                                          \
        aE = fmaf(w6,  EC[22], aE);                                          \
        aF_ = fmaf(w8,  EC[24], aF_);                                        \
        aG = fmaf(w12, EC[28], aG);                                          \
        aH = fmaf(w13, EC[29], aH);                                          \
        aE = fmaf(w14, EC[30], aE);                                          \
        aF_ = fmaf(w9,  EC[25], aF_);                                        \
        aG = fmaf(w10, EC[26], aG);                                          \
        aH = fmaf(w11, EC[27], aH);                                          \
        float q = ((aA + aB) + (aC + aD)) + ((aE + aF_) + (aG + aH));        \
        p  = q * F;                                                          \
        pX = swz16(p);   /* in flight across the step boundary */            \
        /* renorm bookkeeping for next step (off-chain) */                   \
        int bits_ = __builtin_amdgcn_readfirstlane(__float_as_int(p));       \
        int e_ = min(max((bits_ >> 23) & 0xFF, 1), 254);                     \
        kreg = e_ - 127;                                                     \
    }

    for (int ci = 0; ci < nchunk; ++ci) {
        #pragma unroll
        for (int u = 0; u < 8; ++u) {
            float feat = pf[u];
            int   tp   = min(t + 8, NS - 1);
            pf[u] = fb[(size_t)tp * NTAG + j32];       // prefetch t+8
            CRF_STEP(feat)
            ++t;
        }
    }
    // remainder (<8 steps)
    #pragma unroll
    for (int u = 0; u < 7; ++u) {
        if (u < rem) {
            CRF_STEP(pf[u])
            ++t;
        }
    }
    #undef CRF_STEP

    // forward score = c*ln2 + log(sum_j p[j]); p duplicated mod 32
    float s = p;
    #pragma unroll
    for (int m = 1; m <= 16; m <<= 1)
        s += __shfl_xor(s, m, 64);
    float fwd = (float)creg * LN2 + logf(s);

    // ---- gold score: parallel gather tail (latency-tolerant) ----
    float gold = 0.0f;
    #pragma unroll
    for (int k = 0; k < 8; ++k) {
        int tt = (k << 6) + j;
        if (tt < len) {
            int lab_t = lb[tt];
            gold += fb[(size_t)tt * NTAG + lab_t];               // emit
            if (tt > 0)
                gold += trans[(lb[tt - 1] << 5) + lab_t];        // pair
            else
                gold += trans[(TSTART << 5) + lab_t];            // start
            if (tt == len - 1)
                gold += trans[(lab_t << 5) + TSTOP];             // stop
        }
    }
    #pragma unroll
    for (int m = 1; m <= 32; m <<= 1)
        gold += __shfl_xor(gold, m, 64);

    if (j == 0)
        atomicAdd(out, (fwd - gold) * (1.0f / 1024.0f));
}

extern "C" void kernel_launch(void* const* d_in, const int* in_sizes, int n_in,
                              void* d_out, int out_size, void* d_ws, size_t ws_size,
                              hipStream_t stream) {
    const float* feats   = (const float*)d_in[0];
    const int*   labels  = (const int*)d_in[1];
    const int*   lengths = (const int*)d_in[2];
    const float* trans   = (const float*)d_in[3];
    float*       out     = (float*)d_out;

    hipMemsetAsync(out, 0, sizeof(float) * (size_t)out_size, stream);
    crf_fwd<<<dim3(NB), dim3(64), 0, stream>>>(feats, labels, lengths, trans, out);
}